// Round 6
// baseline (44.202 us; speedup 1.0000x reference)
//
#include <hip/hip_runtime.h>
#include <hip/hip_cooperative_groups.h>

namespace cg = cooperative_groups;

// DistributedMemory forward:
//   inputs[b,:] = P[doc_ids[b],:] + sum_c W[context_ids[b,c],:]      [B,128]
//   out[b,s]    = dot(inputs[b,:], outputs[:, sample_ids[b,s]])      [B,S]
// B=16384, C=8, S=10, D=128, N_WORDS=100000, N_DOCS=1e6. All f32.
//
// R5 -> R6: transpose vectorization was neutral (43.3 -> 43.8) => pipeline is
// L3-BW/latency bound, not instruction bound. Fuse both kernels into ONE
// cooperative kernel so the latency-heavy v-build (random P/W gathers)
// overlaps wave-level with the BW-heavy transpose streaming, and the launch
// gap disappears. v stays in registers across the grid sync (no inputs
// round-trip). __threadfence before grid sync publishes dirty outsT lines to
// the memory-side L3 (XCD L2s are not cross-coherent).

#define VEC_DIM 128
#define NW      100000
#define NW4     (NW / 4)
#define CTX     8
#define NSAMP   10
#define TWB     32               // words per transpose tile (NW % 32 == 0)
#define TS      132              // LDS row stride in floats (16B-aligned)
#define NTILES  (NW / TWB)       // 3125
#define COOP_GRID 2048           // == B/8; must be co-resident (8 blocks/CU)

// ---------------- fused cooperative kernel --------------------------------
__global__ __launch_bounds__(256, 8) void dm_fused_coop(
    const int* __restrict__ doc_ids,
    const int* __restrict__ context_ids,
    const int* __restrict__ sample_ids,
    const float* __restrict__ P,       // [N_DOCS,128]
    const float* __restrict__ W,       // [NW,128]
    const float* __restrict__ outs,    // [128,NW]
    float* __restrict__ outsT,         // [NW,128] (ws)
    float* __restrict__ out)           // [B,S]
{
    __shared__ float tile[TWB * TS];   // 16,896 B -> 8 blocks/CU fits 160KB
    const int t    = threadIdx.x;
    const int tsub = t & 31;                       // lane in 32-lane sub-group
    const int b    = blockIdx.x * 8 + (t >> 5);    // batch element (< 16384)

    // ---- phase 0: build inputs[b] in registers (latency-heavy, overlaps
    //      other waves' transpose streaming) ----
    const float4* __restrict__ P4 = (const float4*)P;
    const float4* __restrict__ W4 = (const float4*)W;
    float4 v = P4[doc_ids[b] * 32 + tsub];
    #pragma unroll
    for (int c = 0; c < CTX; ++c) {
        float4 w4 = W4[context_ids[b * CTX + c] * 32 + tsub];
        v.x += w4.x; v.y += w4.y; v.z += w4.z; v.w += w4.w;
    }

    // ---- phase 1: transpose grid-strided tiles (BW-heavy) ----
    const float4* __restrict__ in4 = (const float4*)outs;
    float4* __restrict__ outT4 = (float4*)outsT;
    for (int ti = blockIdx.x; ti < NTILES; ti += COOP_GRID) {
        const int w0 = ti * TWB;
        __syncthreads();                 // tile reuse across iterations
        #pragma unroll
        for (int i = 0; i < 4; ++i) {
            const int f4i = i * 256 + t;
            const int d = f4i >> 3;      // 0..127
            const int u = f4i & 7;       // f4 slot along w
            float4 x = in4[d * NW4 + (w0 >> 2) + u];
            tile[(4 * u + 0) * TS + d] = x.x;
            tile[(4 * u + 1) * TS + d] = x.y;
            tile[(4 * u + 2) * TS + d] = x.z;
            tile[(4 * u + 3) * TS + d] = x.w;
        }
        __syncthreads();
        const float4* tile4 = (const float4*)tile;   // row stride 33 f4
        #pragma unroll
        for (int i = 0; i < 4; ++i) {
            const int f4i = i * 256 + t;
            const int w = f4i >> 5;      // 0..31
            const int q = f4i & 31;      // f4 slot along d
            outT4[(w0 + w) * 32 + q] = tile4[w * 33 + q];
        }
    }

    // ---- publish outsT (device scope) + grid-wide barrier ----
    __threadfence();
    cg::this_grid().sync();

    // ---- phase 2: gather 512B rows + dot ----
    const float4* __restrict__ O4 = (const float4*)outsT;
    int wids[NSAMP];
    #pragma unroll
    for (int s = 0; s < NSAMP; ++s) wids[s] = sample_ids[b * NSAMP + s];

    #pragma unroll
    for (int s = 0; s < NSAMP; ++s) {
        float4 o = O4[wids[s] * 32 + tsub];
        float p = v.x * o.x + v.y * o.y + v.z * o.z + v.w * o.w;
        #pragma unroll
        for (int off = 16; off > 0; off >>= 1)
            p += __shfl_down(p, off, 32);
        if (tsub == 0) out[b * NSAMP + s] = p;
    }
}

// ---------------- fallback path (two kernels, R5 structure) ---------------
__global__ __launch_bounds__(256) void transpose_kernel(
    const float* __restrict__ in, float* __restrict__ outT)
{
    __shared__ float tile[TWB * TS];
    const int t  = threadIdx.x;
    const int w0 = blockIdx.x * TWB;

    const float4* __restrict__ in4 = (const float4*)in;
    #pragma unroll
    for (int i = 0; i < 4; ++i) {
        const int f4i = i * 256 + t;
        const int d = f4i >> 3;
        const int u = f4i & 7;
        float4 v = in4[d * NW4 + (w0 >> 2) + u];
        tile[(4 * u + 0) * TS + d] = v.x;
        tile[(4 * u + 1) * TS + d] = v.y;
        tile[(4 * u + 2) * TS + d] = v.z;
        tile[(4 * u + 3) * TS + d] = v.w;
    }
    __syncthreads();
    float4* __restrict__ outT4 = (float4*)outT;
    const float4* tile4 = (const float4*)tile;
    #pragma unroll
    for (int i = 0; i < 4; ++i) {
        const int f4i = i * 256 + t;
        const int w = f4i >> 5;
        const int q = f4i & 31;
        outT4[(w0 + w) * 32 + q] = tile4[w * 33 + q];
    }
}

__global__ __launch_bounds__(256) void dm_fwd_kernel(
    const int* __restrict__ doc_ids,
    const int* __restrict__ context_ids,
    const int* __restrict__ sample_ids,
    const float* __restrict__ P,
    const float* __restrict__ W,
    const float* __restrict__ outsT,
    float* __restrict__ out)
{
    const int t = threadIdx.x & 31;
    const int b = blockIdx.x * 8 + (threadIdx.x >> 5);

    const float4* __restrict__ P4 = (const float4*)P;
    const float4* __restrict__ W4 = (const float4*)W;
    const float4* __restrict__ O4 = (const float4*)outsT;

    float4 v = P4[doc_ids[b] * 32 + t];
    #pragma unroll
    for (int c = 0; c < CTX; ++c) {
        float4 w4 = W4[context_ids[b * CTX + c] * 32 + t];
        v.x += w4.x; v.y += w4.y; v.z += w4.z; v.w += w4.w;
    }

    int wids[NSAMP];
    #pragma unroll
    for (int s = 0; s < NSAMP; ++s) wids[s] = sample_ids[b * NSAMP + s];

    #pragma unroll
    for (int s = 0; s < NSAMP; ++s) {
        float4 o = O4[wids[s] * 32 + t];
        float p = v.x * o.x + v.y * o.y + v.z * o.z + v.w * o.w;
        #pragma unroll
        for (int off = 16; off > 0; off >>= 1)
            p += __shfl_down(p, off, 32);
        if (t == 0) out[b * NSAMP + s] = p;
    }
}

extern "C" void kernel_launch(void* const* d_in, const int* in_sizes, int n_in,
                              void* d_out, int out_size, void* d_ws, size_t ws_size,
                              hipStream_t stream) {
    const int* doc_ids     = (const int*)d_in[0];
    const int* context_ids = (const int*)d_in[1];
    const int* sample_ids  = (const int*)d_in[2];
    const float* P         = (const float*)d_in[3];
    const float* W         = (const float*)d_in[4];
    const float* outs      = (const float*)d_in[5];
    float* out             = (float*)d_out;

    const int B = in_sizes[0];  // 16384
    const size_t needed = (size_t)NW * VEC_DIM * sizeof(float);  // 51.2 MB
    float* outsT = (float*)d_ws;

    bool coop_ok = (ws_size >= needed) && (B == 16384);
    if (coop_ok) {
        int max_blocks_per_cu = 0;
        hipError_t qerr = hipOccupancyMaxActiveBlocksPerMultiprocessor(
            &max_blocks_per_cu, (const void*)dm_fused_coop, 256, 0);
        if (qerr != hipSuccess || max_blocks_per_cu < 8) coop_ok = false;
    }

    if (coop_ok) {
        void* args[] = {
            (void*)&doc_ids, (void*)&context_ids, (void*)&sample_ids,
            (void*)&P, (void*)&W, (void*)&outs, (void*)&outsT, (void*)&out
        };
        hipError_t lerr = hipLaunchCooperativeKernel(
            (const void*)dm_fused_coop, dim3(COOP_GRID), dim3(256),
            args, 0, stream);
        if (lerr == hipSuccess) return;
        // fall through to two-kernel path if coop launch refused
    }

    if (ws_size >= needed) {
        transpose_kernel<<<NW / TWB, 256, 0, stream>>>(outs, outsT);
        dm_fwd_kernel<<<B / 8, 256, 0, stream>>>(doc_ids, context_ids, sample_ids,
                                                 P, W, outsT, out);
    }
}